// Round 4
// baseline (1175.114 us; speedup 1.0000x reference)
//
#include <hip/hip_runtime.h>
#include <stdint.h>

#define N_NODES 100000
#define N_EDGES 1600000
#define N_SCAN_BLOCKS ((N_NODES + 1023) / 1024)   // 98
#define N_BUCKETS ((N_NODES + 255) / 256)         // 391

typedef __attribute__((ext_vector_type(8))) short bf16x8;
typedef __attribute__((ext_vector_type(4))) float f32x4;

__device__ __forceinline__ uint32_t f2bf(float f) {
  uint32_t u = __float_as_uint(f);
  u += 0x7fffu + ((u >> 16) & 1);   // RNE
  return u >> 16;
}
__device__ __forceinline__ float bf_lo(uint32_t v) { return __uint_as_float(v << 16); }
__device__ __forceinline__ float bf_hi(uint32_t v) { return __uint_as_float(v & 0xffff0000u); }
__device__ __forceinline__ uint32_t pack2(float a, float b) { return f2bf(a) | (f2bf(b) << 16); }

// ---------- CSR build ----------
__global__ void k_hist(const int* __restrict__ dst, int* __restrict__ deg) {
  int e = blockIdx.x * 256 + threadIdx.x;
  if (e < N_EDGES) atomicAdd(&deg[dst[e]], 1);
}

// Hierarchical scan stage 1: per-block (1024 elems) exclusive scan + block total.
__global__ __launch_bounds__(256) void k_scan_local(const int* __restrict__ deg,
                                                    int* __restrict__ row_ptr,
                                                    int* __restrict__ blocksum) {
  __shared__ int lds[256];
  int base = blockIdx.x * 1024 + threadIdx.x * 4;
  int v0 = (base     < N_NODES) ? deg[base]     : 0;
  int v1 = (base + 1 < N_NODES) ? deg[base + 1] : 0;
  int v2 = (base + 2 < N_NODES) ? deg[base + 2] : 0;
  int v3 = (base + 3 < N_NODES) ? deg[base + 3] : 0;
  int tsum = v0 + v1 + v2 + v3;
  lds[threadIdx.x] = tsum;
  __syncthreads();
  for (int off = 1; off < 256; off <<= 1) {
    int t = (threadIdx.x >= (unsigned)off) ? lds[threadIdx.x - off] : 0;
    __syncthreads();
    lds[threadIdx.x] += t;
    __syncthreads();
  }
  int run = lds[threadIdx.x] - tsum;   // exclusive prefix of this thread's chunk
  if (base     < N_NODES) row_ptr[base]     = run;            run += v0;
  if (base + 1 < N_NODES) row_ptr[base + 1] = run;            run += v1;
  if (base + 2 < N_NODES) row_ptr[base + 2] = run;            run += v2;
  if (base + 3 < N_NODES) row_ptr[base + 3] = run;
  if (threadIdx.x == 255) blocksum[blockIdx.x] = lds[255];
}

// Stage 2: exclusive scan of the 98 block sums (single tiny block).
__global__ __launch_bounds__(128) void k_scan_blocks(int* __restrict__ blocksum) {
  __shared__ int lds[128];
  int v = (threadIdx.x < N_SCAN_BLOCKS) ? blocksum[threadIdx.x] : 0;
  lds[threadIdx.x] = v;
  __syncthreads();
  for (int off = 1; off < 128; off <<= 1) {
    int t = (threadIdx.x >= (unsigned)off) ? lds[threadIdx.x - off] : 0;
    __syncthreads();
    lds[threadIdx.x] += t;
    __syncthreads();
  }
  if (threadIdx.x < N_SCAN_BLOCKS) blocksum[threadIdx.x] = lds[threadIdx.x] - v;  // exclusive
}

// Stage 3: add block offsets; row_ptr[N] is the compile-time edge count.
__global__ __launch_bounds__(256) void k_scan_add(int* __restrict__ row_ptr,
                                                  const int* __restrict__ blocksum) {
  int i = blockIdx.x * 256 + threadIdx.x;
  if (i < N_NODES) row_ptr[i] += blocksum[i >> 10];
  if (i == 0) row_ptr[N_NODES] = N_EDGES;
}

// Bucket pass 1: append edge records into per-bucket staging ranges.
// Bucket b covers dst in [b*256,(b+1)*256); its staging range is
// [row_ptr[b*256], row_ptr[(b+1)*256]) — appends are consecutive, so L2
// lines fill completely (writes ~12.8 MB instead of ~150 MB scattered).
__global__ void k_bucket(const int* __restrict__ src, const int* __restrict__ dst,
                         const float* __restrict__ w, const int* __restrict__ row_ptr,
                         int* __restrict__ cur, int2* __restrict__ staging) {
  int e = blockIdx.x * 256 + threadIdx.x;
  if (e >= N_EDGES) return;
  int d = dst[e];
  int b = d >> 8;
  int base = row_ptr[b << 8];
  int pos = base + atomicAdd(&cur[b], 1);
  staging[pos] = make_int2(((d & 255) << 24) | src[e], __float_as_int(w[e]));
}

// Bucket pass 2: one block per bucket; place records at exact CSR slots.
// Random writes stay inside the bucket's ~32 KB output window (L2-local).
__global__ __launch_bounds__(256) void k_localize(const int2* __restrict__ staging,
                                                  const int* __restrict__ row_ptr,
                                                  int* __restrict__ fill,
                                                  int2* __restrict__ rec) {
  int b = blockIdx.x;
  int lo = row_ptr[b << 8];
  int hi = row_ptr[min((b + 1) << 8, N_NODES)];
  for (int i = lo + (int)threadIdx.x; i < hi; i += 256) {
    int2 r = staging[i];
    int d = (b << 8) + ((unsigned)r.x >> 24);
    int pos = row_ptr[d] + atomicAdd(&fill[d], 1);
    rec[pos] = make_int2(r.x & 0x00ffffff, r.y);
  }
}

// ---------- pack fp32 weights -> bf16, transposed [n][k] ----------
__global__ void k_pack(const float* __restrict__ w1, const float* __restrict__ wp,
                       const float* __restrict__ w2, uint16_t* __restrict__ wT1,
                       uint16_t* __restrict__ wTc) {
  int i = blockIdx.x * 256 + threadIdx.x;
  if (i < 128 * 256) {            // wT1[n*256+k] = bf16(w1[k*128+n])
    int n = i >> 8, k = i & 255;
    wT1[n * 256 + k] = (uint16_t)f2bf(w1[k * 128 + n]);
  }
  int j = i - 128 * 256;
  if (j >= 0 && j < 128 * 128) {  // wTc[n*128+k] = bf16([wp|w2] col n, row k)
    int n = j >> 7, k = j & 127;
    wTc[n * 128 + k] = (uint16_t)f2bf((n < 64) ? wp[k * 64 + n] : w2[k * 64 + (n - 64)]);
  }
}

// ---------- GEMM1: A[M,256]fp32 @ W[256,128]bf16 -> C[M,128]bf16 ----------
__global__ __launch_bounds__(256) void k_gemm1(const float* __restrict__ A,
                                               const uint16_t* __restrict__ wT,
                                               uint16_t* __restrict__ C, int M) {
  int wave = threadIdx.x >> 6, lane = threadIdx.x & 63;
  int m0 = (blockIdx.x * 4 + wave) * 16;
  int quad = lane >> 4, mcol = lane & 15;
  int arow = m0 + mcol;
  bool av = arow < M;

  f32x4 acc[8];
#pragma unroll
  for (int nt = 0; nt < 8; nt++) acc[nt] = (f32x4){0.f, 0.f, 0.f, 0.f};

  for (int k0 = 0; k0 < 256; k0 += 32) {
    bf16x8 a = {};
    if (av) {
      const float* ap = A + (size_t)arow * 256 + k0 + quad * 8;
      float4 lo = *(const float4*)ap;
      float4 hi = *(const float4*)(ap + 4);
      a[0] = (short)f2bf(lo.x); a[1] = (short)f2bf(lo.y);
      a[2] = (short)f2bf(lo.z); a[3] = (short)f2bf(lo.w);
      a[4] = (short)f2bf(hi.x); a[5] = (short)f2bf(hi.y);
      a[6] = (short)f2bf(hi.z); a[7] = (short)f2bf(hi.w);
    }
#pragma unroll
    for (int nt = 0; nt < 8; nt++) {
      bf16x8 b = *(const bf16x8*)(wT + (size_t)(nt * 16 + mcol) * 256 + k0 + quad * 8);
      acc[nt] = __builtin_amdgcn_mfma_f32_16x16x32_bf16(a, b, acc[nt], 0, 0, 0);
    }
  }
#pragma unroll
  for (int r = 0; r < 4; r++) {
    int row = m0 + quad * 4 + r;
    if (row < M) {
#pragma unroll
      for (int nt = 0; nt < 8; nt++)
        C[(size_t)row * 128 + nt * 16 + mcol] = (uint16_t)f2bf(acc[nt][r]);
    }
  }
}

// ---------- GEMM2: A[M,128]bf16 @ W[128,128]bf16 -> C[M,128]bf16 ----------
__global__ __launch_bounds__(256) void k_gemm2(const uint16_t* __restrict__ A,
                                               const uint16_t* __restrict__ wT,
                                               uint16_t* __restrict__ C, int M) {
  int wave = threadIdx.x >> 6, lane = threadIdx.x & 63;
  int m0 = (blockIdx.x * 4 + wave) * 16;
  int quad = lane >> 4, mcol = lane & 15;
  int arow = m0 + mcol;
  bool av = arow < M;

  f32x4 acc[8];
#pragma unroll
  for (int nt = 0; nt < 8; nt++) acc[nt] = (f32x4){0.f, 0.f, 0.f, 0.f};

  for (int k0 = 0; k0 < 128; k0 += 32) {
    bf16x8 a = {};
    if (av) a = *(const bf16x8*)(A + (size_t)arow * 128 + k0 + quad * 8);
#pragma unroll
    for (int nt = 0; nt < 8; nt++) {
      bf16x8 b = *(const bf16x8*)(wT + (size_t)(nt * 16 + mcol) * 128 + k0 + quad * 8);
      acc[nt] = __builtin_amdgcn_mfma_f32_16x16x32_bf16(a, b, acc[nt], 0, 0, 0);
    }
  }
#pragma unroll
  for (int r = 0; r < 4; r++) {
    int row = m0 + quad * 4 + r;
    if (row < M) {
#pragma unroll
      for (int nt = 0; nt < 8; nt++)
        C[(size_t)row * 128 + nt * 16 + mcol] = (uint16_t)f2bf(acc[nt][r]);
    }
  }
}

// ---------- SpMM: agg[r,:] = sum_e w_e * support[src_e,:]  (CSR, 1 wave/row) ----------
__global__ __launch_bounds__(256) void k_spmm(const uint16_t* __restrict__ sup,
                                              const int* __restrict__ row_ptr,
                                              const int2* __restrict__ rec,
                                              uint16_t* __restrict__ agg) {
  int row = blockIdx.x * 4 + (threadIdx.x >> 6);
  if (row >= N_NODES) return;
  int lane = threadIdx.x & 63;
  int s = row_ptr[row], e = row_ptr[row + 1];
  float a0 = 0.f, a1 = 0.f;
  int i = s;
  for (; i + 4 <= e; i += 4) {
    int2 r0 = rec[i], r1 = rec[i + 1], r2 = rec[i + 2], r3 = rec[i + 3];
    uint32_t v0 = *(const uint32_t*)(sup + (size_t)r0.x * 128 + lane * 2);
    uint32_t v1 = *(const uint32_t*)(sup + (size_t)r1.x * 128 + lane * 2);
    uint32_t v2 = *(const uint32_t*)(sup + (size_t)r2.x * 128 + lane * 2);
    uint32_t v3 = *(const uint32_t*)(sup + (size_t)r3.x * 128 + lane * 2);
    float w0 = __int_as_float(r0.y), w1 = __int_as_float(r1.y);
    float w2 = __int_as_float(r2.y), w3 = __int_as_float(r3.y);
    a0 += w0 * bf_lo(v0) + w1 * bf_lo(v1) + w2 * bf_lo(v2) + w3 * bf_lo(v3);
    a1 += w0 * bf_hi(v0) + w1 * bf_hi(v1) + w2 * bf_hi(v2) + w3 * bf_hi(v3);
  }
  for (; i < e; i++) {
    int2 r = rec[i];
    uint32_t v = *(const uint32_t*)(sup + (size_t)r.x * 128 + lane * 2);
    float w = __int_as_float(r.y);
    a0 += w * bf_lo(v);
    a1 += w * bf_hi(v);
  }
  *(uint32_t*)(agg + (size_t)row * 128 + lane * 2) = pack2(a0, a1);
}

// ---------- column sums (for PairNorm centering) ----------
__global__ __launch_bounds__(256) void k_colsum(const uint16_t* __restrict__ agg,
                                                float* __restrict__ cs) {
  __shared__ float sd[256];
  int col = threadIdx.x & 127, half = threadIdx.x >> 7;
  int r0 = blockIdx.x * 256;
  float local = 0.f;
  for (int r = r0 + half; r < r0 + 256 && r < N_NODES; r += 2)
    local += __uint_as_float(((uint32_t)agg[(size_t)r * 128 + col]) << 16);
  sd[threadIdx.x] = local;
  __syncthreads();
  if (threadIdx.x < 128) atomicAdd(&cs[col], sd[threadIdx.x] + sd[threadIdx.x + 128]);
}

// ---------- PairNorm-SI + ReLU, IN PLACE on agg (bf16) ----------
__global__ __launch_bounds__(256) void k_pn1(uint16_t* __restrict__ agg,
                                             const float* __restrict__ cs) {
  int row = blockIdx.x * 4 + (threadIdx.x >> 6);
  if (row >= N_NODES) return;
  int lane = threadIdx.x & 63;
  const float invn = 1.0f / (float)N_NODES;
  uint32_t v = *(const uint32_t*)(agg + (size_t)row * 128 + lane * 2);
  float h0 = bf_lo(v) - cs[lane * 2] * invn;
  float h1 = bf_hi(v) - cs[lane * 2 + 1] * invn;
  float ss = h0 * h0 + h1 * h1;
#pragma unroll
  for (int m = 1; m < 64; m <<= 1) ss += __shfl_xor(ss, m, 64);
  float rinv = rsqrtf(1e-6f + ss);
  *(uint32_t*)(agg + (size_t)row * 128 + lane * 2) =
      pack2(fmaxf(h0 * rinv, 0.f), fmaxf(h1 * rinv, 0.f));
}

// ---------- final: agg cols 0..63 -> pool1 (pairnorm+softmax), 64..127 -> enc2 (pairnorm+relu), fp32 out ----------
__global__ __launch_bounds__(256) void k_final(const uint16_t* __restrict__ agg,
                                               const float* __restrict__ cs,
                                               float* __restrict__ out) {
  int row = blockIdx.x * 4 + (threadIdx.x >> 6);
  if (row >= N_NODES) return;
  int lane = threadIdx.x & 63;
  const float invn = 1.0f / (float)N_NODES;
  uint32_t v = *(const uint32_t*)(agg + (size_t)row * 128 + lane * 2);
  float h0 = bf_lo(v) - cs[lane * 2] * invn;
  float h1 = bf_hi(v) - cs[lane * 2 + 1] * invn;
  float ss = h0 * h0 + h1 * h1;
#pragma unroll
  for (int m = 1; m < 32; m <<= 1) ss += __shfl_xor(ss, m, 64);  // half-wave reduce (each 64-col half separately)
  float rinv = rsqrtf(1e-6f + ss);
  float p0 = h0 * rinv, p1 = h1 * rinv;
  if (lane < 32) {  // pool half: softmax over 64 cols spread across lanes 0..31
    float mx = fmaxf(p0, p1);
#pragma unroll
    for (int m = 1; m < 32; m <<= 1) mx = fmaxf(mx, __shfl_xor(mx, m, 64));
    float e0 = __expf(p0 - mx), e1 = __expf(p1 - mx);
    float sum = e0 + e1;
#pragma unroll
    for (int m = 1; m < 32; m <<= 1) sum += __shfl_xor(sum, m, 64);
    float inv = 1.0f / sum;
    float2 o = {e0 * inv, e1 * inv};
    *(float2*)(out + (size_t)N_NODES * 64 + (size_t)row * 64 + lane * 2) = o;  // pool1 second
  } else {          // enc half: relu
    int l = lane - 32;
    float2 o = {fmaxf(p0, 0.f), fmaxf(p1, 0.f)};
    *(float2*)(out + (size_t)row * 64 + l * 2) = o;                            // enc2 first
  }
}

extern "C" void kernel_launch(void* const* d_in, const int* in_sizes, int n_in,
                              void* d_out, int out_size, void* d_ws, size_t ws_size,
                              hipStream_t stream) {
  const float* x    = (const float*)d_in[0];
  const int*   esrc = (const int*)d_in[1];
  const int*   edst = (const int*)d_in[2];
  const float* ew   = (const float*)d_in[3];
  const float* w1   = (const float*)d_in[4];
  // d_in[5]=b1, d_in[7]=bp, d_in[9]=b2 are zero AND cancel under PairNorm centering
  const float* wp   = (const float*)d_in[6];
  const float* w2   = (const float*)d_in[8];
  float* out = (float*)d_out;

  char* ws = (char*)d_ws;
  size_t off = 0;
  auto alloc = [&](size_t bytes) {
    char* p = ws + off;
    off += (bytes + 255) & ~(size_t)255;
    return p;
  };
  uint16_t* support = (uint16_t*)alloc((size_t)N_NODES * 128 * 2);  // bf16
  uint16_t* agg     = (uint16_t*)alloc((size_t)N_NODES * 128 * 2);  // bf16; doubles as staging pre-spmm
  int2*     rec     = (int2*)alloc((size_t)N_EDGES * 8);            // packed {src, w}
  int*      row_ptr = (int*)alloc((size_t)(N_NODES + 1) * 4);
  int*      bsum    = (int*)alloc((size_t)N_SCAN_BLOCKS * 4);
  size_t zero_start = off;
  int*      deg     = (int*)alloc((size_t)N_NODES * 4);
  int*      fill    = (int*)alloc((size_t)N_NODES * 4);
  int*      cur     = (int*)alloc((size_t)N_BUCKETS * 4);
  float*    cs      = (float*)alloc(256 * 4);
  size_t zero_bytes = off - zero_start;
  uint16_t* wT1     = (uint16_t*)alloc(128 * 256 * 2);
  uint16_t* wTc     = (uint16_t*)alloc(128 * 128 * 2);
  int2*     staging = (int2*)agg;   // agg region is free until first k_spmm
  (void)ws_size; (void)in_sizes; (void)n_in; (void)out_size;

  hipMemsetAsync(deg, 0, zero_bytes, stream);

  // CSR build (reused by both SpMMs)
  k_hist<<<(N_EDGES + 255) / 256, 256, 0, stream>>>(edst, deg);
  k_scan_local<<<N_SCAN_BLOCKS, 256, 0, stream>>>(deg, row_ptr, bsum);
  k_scan_blocks<<<1, 128, 0, stream>>>(bsum);
  k_scan_add<<<(N_NODES + 255) / 256, 256, 0, stream>>>(row_ptr, bsum);
  k_bucket<<<(N_EDGES + 255) / 256, 256, 0, stream>>>(esrc, edst, ew, row_ptr, cur, staging);
  k_localize<<<N_BUCKETS, 256, 0, stream>>>(staging, row_ptr, fill, rec);
  k_pack<<<192, 256, 0, stream>>>(w1, wp, w2, wT1, wTc);

  // Layer 1
  k_gemm1<<<(N_NODES + 63) / 64, 256, 0, stream>>>(x, wT1, support, N_NODES);
  k_spmm<<<(N_NODES + 3) / 4, 256, 0, stream>>>(support, row_ptr, rec, agg);
  k_colsum<<<(N_NODES + 255) / 256, 256, 0, stream>>>(agg, cs);
  k_pn1<<<(N_NODES + 3) / 4, 256, 0, stream>>>(agg, cs);  // agg := enc1 (in place)

  // Layer 2 (pool + enc fused: support_cat = enc1 @ [wp|w2])
  k_gemm2<<<(N_NODES + 63) / 64, 256, 0, stream>>>(agg, wTc, support, N_NODES);
  k_spmm<<<(N_NODES + 3) / 4, 256, 0, stream>>>(support, row_ptr, rec, agg);
  k_colsum<<<(N_NODES + 255) / 256, 256, 0, stream>>>(agg, cs + 128);
  k_final<<<(N_NODES + 3) / 4, 256, 0, stream>>>(agg, cs + 128, out);
}

// Round 5
// 673.477 us; speedup vs baseline: 1.7448x; 1.7448x over previous
//
#include <hip/hip_runtime.h>
#include <stdint.h>

#define N_NODES 100000
#define N_EDGES 1600000
#define N_SCAN_BLOCKS ((N_NODES + 1023) / 1024)   // 98

typedef __attribute__((ext_vector_type(8))) short bf16x8;
typedef __attribute__((ext_vector_type(4))) float f32x4;

__device__ __forceinline__ uint32_t f2bf(float f) {
  uint32_t u = __float_as_uint(f);
  u += 0x7fffu + ((u >> 16) & 1);   // RNE
  return u >> 16;
}
__device__ __forceinline__ float bf_lo(uint32_t v) { return __uint_as_float(v << 16); }
__device__ __forceinline__ float bf_hi(uint32_t v) { return __uint_as_float(v & 0xffff0000u); }
__device__ __forceinline__ uint32_t pack2(float a, float b) { return f2bf(a) | (f2bf(b) << 16); }

// ---------- CSR build ----------
__global__ void k_hist(const int* __restrict__ dst, int* __restrict__ deg) {
  int e = blockIdx.x * 256 + threadIdx.x;
  if (e < N_EDGES) atomicAdd(&deg[dst[e]], 1);
}

// Hierarchical scan stage 1: per-block (1024 elems) exclusive scan + block total.
__global__ __launch_bounds__(256) void k_scan_local(const int* __restrict__ deg,
                                                    int* __restrict__ row_ptr,
                                                    int* __restrict__ blocksum) {
  __shared__ int lds[256];
  int base = blockIdx.x * 1024 + threadIdx.x * 4;
  int v0 = (base     < N_NODES) ? deg[base]     : 0;
  int v1 = (base + 1 < N_NODES) ? deg[base + 1] : 0;
  int v2 = (base + 2 < N_NODES) ? deg[base + 2] : 0;
  int v3 = (base + 3 < N_NODES) ? deg[base + 3] : 0;
  int tsum = v0 + v1 + v2 + v3;
  lds[threadIdx.x] = tsum;
  __syncthreads();
  for (int off = 1; off < 256; off <<= 1) {
    int t = (threadIdx.x >= (unsigned)off) ? lds[threadIdx.x - off] : 0;
    __syncthreads();
    lds[threadIdx.x] += t;
    __syncthreads();
  }
  int run = lds[threadIdx.x] - tsum;   // exclusive prefix of this thread's chunk
  if (base     < N_NODES) row_ptr[base]     = run;            run += v0;
  if (base + 1 < N_NODES) row_ptr[base + 1] = run;            run += v1;
  if (base + 2 < N_NODES) row_ptr[base + 2] = run;            run += v2;
  if (base + 3 < N_NODES) row_ptr[base + 3] = run;
  if (threadIdx.x == 255) blocksum[blockIdx.x] = lds[255];
}

// Stage 2: exclusive scan of the 98 block sums (single tiny block).
__global__ __launch_bounds__(128) void k_scan_blocks(int* __restrict__ blocksum) {
  __shared__ int lds[128];
  int v = (threadIdx.x < N_SCAN_BLOCKS) ? blocksum[threadIdx.x] : 0;
  lds[threadIdx.x] = v;
  __syncthreads();
  for (int off = 1; off < 128; off <<= 1) {
    int t = (threadIdx.x >= (unsigned)off) ? lds[threadIdx.x - off] : 0;
    __syncthreads();
    lds[threadIdx.x] += t;
    __syncthreads();
  }
  if (threadIdx.x < N_SCAN_BLOCKS) blocksum[threadIdx.x] = lds[threadIdx.x] - v;  // exclusive
}

// Stage 3: add block offsets; row_ptr[N] is the compile-time edge count.
__global__ __launch_bounds__(256) void k_scan_add(int* __restrict__ row_ptr,
                                                  const int* __restrict__ blocksum) {
  int i = blockIdx.x * 256 + threadIdx.x;
  if (i < N_NODES) row_ptr[i] += blocksum[i >> 10];
  if (i == 0) row_ptr[N_NODES] = N_EDGES;
}

// Direct scatter with per-node fill counters (100k counters -> ~16 atomics each,
// no hot-counter serialization; the 391-counter bucket variant measured 557us).
// ONE packed 8B store per edge (vs two 4B stores to two arrays) halves the
// number of randomly-dirtied cache lines.
__global__ void k_scatter(const int* __restrict__ src, const int* __restrict__ dst,
                          const float* __restrict__ w, const int* __restrict__ row_ptr,
                          int* __restrict__ fill, int2* __restrict__ rec) {
  int e = blockIdx.x * 256 + threadIdx.x;
  if (e < N_EDGES) {
    int d = dst[e];
    int pos = row_ptr[d] + atomicAdd(&fill[d], 1);
    rec[pos] = make_int2(src[e], __float_as_int(w[e]));
  }
}

// ---------- pack fp32 weights -> bf16, transposed [n][k] ----------
__global__ void k_pack(const float* __restrict__ w1, const float* __restrict__ wp,
                       const float* __restrict__ w2, uint16_t* __restrict__ wT1,
                       uint16_t* __restrict__ wTc) {
  int i = blockIdx.x * 256 + threadIdx.x;
  if (i < 128 * 256) {            // wT1[n*256+k] = bf16(w1[k*128+n])
    int n = i >> 8, k = i & 255;
    wT1[n * 256 + k] = (uint16_t)f2bf(w1[k * 128 + n]);
  }
  int j = i - 128 * 256;
  if (j >= 0 && j < 128 * 128) {  // wTc[n*128+k] = bf16([wp|w2] col n, row k)
    int n = j >> 7, k = j & 127;
    wTc[n * 128 + k] = (uint16_t)f2bf((n < 64) ? wp[k * 64 + n] : w2[k * 64 + (n - 64)]);
  }
}

// ---------- GEMM1: A[M,256]fp32 @ W[256,128]bf16 -> C[M,128]bf16 ----------
__global__ __launch_bounds__(256) void k_gemm1(const float* __restrict__ A,
                                               const uint16_t* __restrict__ wT,
                                               uint16_t* __restrict__ C, int M) {
  int wave = threadIdx.x >> 6, lane = threadIdx.x & 63;
  int m0 = (blockIdx.x * 4 + wave) * 16;
  int quad = lane >> 4, mcol = lane & 15;
  int arow = m0 + mcol;
  bool av = arow < M;

  f32x4 acc[8];
#pragma unroll
  for (int nt = 0; nt < 8; nt++) acc[nt] = (f32x4){0.f, 0.f, 0.f, 0.f};

  for (int k0 = 0; k0 < 256; k0 += 32) {
    bf16x8 a = {};
    if (av) {
      const float* ap = A + (size_t)arow * 256 + k0 + quad * 8;
      float4 lo = *(const float4*)ap;
      float4 hi = *(const float4*)(ap + 4);
      a[0] = (short)f2bf(lo.x); a[1] = (short)f2bf(lo.y);
      a[2] = (short)f2bf(lo.z); a[3] = (short)f2bf(lo.w);
      a[4] = (short)f2bf(hi.x); a[5] = (short)f2bf(hi.y);
      a[6] = (short)f2bf(hi.z); a[7] = (short)f2bf(hi.w);
    }
#pragma unroll
    for (int nt = 0; nt < 8; nt++) {
      bf16x8 b = *(const bf16x8*)(wT + (size_t)(nt * 16 + mcol) * 256 + k0 + quad * 8);
      acc[nt] = __builtin_amdgcn_mfma_f32_16x16x32_bf16(a, b, acc[nt], 0, 0, 0);
    }
  }
#pragma unroll
  for (int r = 0; r < 4; r++) {
    int row = m0 + quad * 4 + r;
    if (row < M) {
#pragma unroll
      for (int nt = 0; nt < 8; nt++)
        C[(size_t)row * 128 + nt * 16 + mcol] = (uint16_t)f2bf(acc[nt][r]);
    }
  }
}

// ---------- GEMM2: A[M,128]bf16 @ W[128,128]bf16 -> C[M,128]bf16 ----------
__global__ __launch_bounds__(256) void k_gemm2(const uint16_t* __restrict__ A,
                                               const uint16_t* __restrict__ wT,
                                               uint16_t* __restrict__ C, int M) {
  int wave = threadIdx.x >> 6, lane = threadIdx.x & 63;
  int m0 = (blockIdx.x * 4 + wave) * 16;
  int quad = lane >> 4, mcol = lane & 15;
  int arow = m0 + mcol;
  bool av = arow < M;

  f32x4 acc[8];
#pragma unroll
  for (int nt = 0; nt < 8; nt++) acc[nt] = (f32x4){0.f, 0.f, 0.f, 0.f};

  for (int k0 = 0; k0 < 128; k0 += 32) {
    bf16x8 a = {};
    if (av) a = *(const bf16x8*)(A + (size_t)arow * 128 + k0 + quad * 8);
#pragma unroll
    for (int nt = 0; nt < 8; nt++) {
      bf16x8 b = *(const bf16x8*)(wT + (size_t)(nt * 16 + mcol) * 128 + k0 + quad * 8);
      acc[nt] = __builtin_amdgcn_mfma_f32_16x16x32_bf16(a, b, acc[nt], 0, 0, 0);
    }
  }
#pragma unroll
  for (int r = 0; r < 4; r++) {
    int row = m0 + quad * 4 + r;
    if (row < M) {
#pragma unroll
      for (int nt = 0; nt < 8; nt++)
        C[(size_t)row * 128 + nt * 16 + mcol] = (uint16_t)f2bf(acc[nt][r]);
    }
  }
}

// ---------- SpMM: agg[r,:] = sum_e w_e * support[src_e,:]  (CSR, 1 wave/row, unroll 8) ----------
__global__ __launch_bounds__(256) void k_spmm(const uint16_t* __restrict__ sup,
                                              const int* __restrict__ row_ptr,
                                              const int2* __restrict__ rec,
                                              uint16_t* __restrict__ agg) {
  int row = blockIdx.x * 4 + (threadIdx.x >> 6);
  if (row >= N_NODES) return;
  int lane = threadIdx.x & 63;
  int s = row_ptr[row], e = row_ptr[row + 1];
  float a0 = 0.f, a1 = 0.f;
  int i = s;
  for (; i + 8 <= e; i += 8) {
    int2 r[8];
    uint32_t v[8];
#pragma unroll
    for (int u = 0; u < 8; u++) r[u] = rec[i + u];
#pragma unroll
    for (int u = 0; u < 8; u++)
      v[u] = *(const uint32_t*)(sup + (size_t)r[u].x * 128 + lane * 2);
#pragma unroll
    for (int u = 0; u < 8; u++) {
      float w = __int_as_float(r[u].y);
      a0 += w * bf_lo(v[u]);
      a1 += w * bf_hi(v[u]);
    }
  }
  for (; i < e; i++) {
    int2 r = rec[i];
    uint32_t v = *(const uint32_t*)(sup + (size_t)r.x * 128 + lane * 2);
    float w = __int_as_float(r.y);
    a0 += w * bf_lo(v);
    a1 += w * bf_hi(v);
  }
  *(uint32_t*)(agg + (size_t)row * 128 + lane * 2) = pack2(a0, a1);
}

// ---------- column sums (for PairNorm centering) ----------
__global__ __launch_bounds__(256) void k_colsum(const uint16_t* __restrict__ agg,
                                                float* __restrict__ cs) {
  __shared__ float sd[256];
  int col = threadIdx.x & 127, half = threadIdx.x >> 7;
  int r0 = blockIdx.x * 256;
  float local = 0.f;
  for (int r = r0 + half; r < r0 + 256 && r < N_NODES; r += 2)
    local += __uint_as_float(((uint32_t)agg[(size_t)r * 128 + col]) << 16);
  sd[threadIdx.x] = local;
  __syncthreads();
  if (threadIdx.x < 128) atomicAdd(&cs[col], sd[threadIdx.x] + sd[threadIdx.x + 128]);
}

// ---------- PairNorm-SI + ReLU, IN PLACE on agg (bf16) ----------
__global__ __launch_bounds__(256) void k_pn1(uint16_t* __restrict__ agg,
                                             const float* __restrict__ cs) {
  int row = blockIdx.x * 4 + (threadIdx.x >> 6);
  if (row >= N_NODES) return;
  int lane = threadIdx.x & 63;
  const float invn = 1.0f / (float)N_NODES;
  uint32_t v = *(const uint32_t*)(agg + (size_t)row * 128 + lane * 2);
  float h0 = bf_lo(v) - cs[lane * 2] * invn;
  float h1 = bf_hi(v) - cs[lane * 2 + 1] * invn;
  float ss = h0 * h0 + h1 * h1;
#pragma unroll
  for (int m = 1; m < 64; m <<= 1) ss += __shfl_xor(ss, m, 64);
  float rinv = rsqrtf(1e-6f + ss);
  *(uint32_t*)(agg + (size_t)row * 128 + lane * 2) =
      pack2(fmaxf(h0 * rinv, 0.f), fmaxf(h1 * rinv, 0.f));
}

// ---------- final: agg cols 0..63 -> pool1 (pairnorm+softmax), 64..127 -> enc2 (pairnorm+relu), fp32 out ----------
__global__ __launch_bounds__(256) void k_final(const uint16_t* __restrict__ agg,
                                               const float* __restrict__ cs,
                                               float* __restrict__ out) {
  int row = blockIdx.x * 4 + (threadIdx.x >> 6);
  if (row >= N_NODES) return;
  int lane = threadIdx.x & 63;
  const float invn = 1.0f / (float)N_NODES;
  uint32_t v = *(const uint32_t*)(agg + (size_t)row * 128 + lane * 2);
  float h0 = bf_lo(v) - cs[lane * 2] * invn;
  float h1 = bf_hi(v) - cs[lane * 2 + 1] * invn;
  float ss = h0 * h0 + h1 * h1;
#pragma unroll
  for (int m = 1; m < 32; m <<= 1) ss += __shfl_xor(ss, m, 64);  // half-wave reduce (each 64-col half separately)
  float rinv = rsqrtf(1e-6f + ss);
  float p0 = h0 * rinv, p1 = h1 * rinv;
  if (lane < 32) {  // pool half: softmax over 64 cols spread across lanes 0..31
    float mx = fmaxf(p0, p1);
#pragma unroll
    for (int m = 1; m < 32; m <<= 1) mx = fmaxf(mx, __shfl_xor(mx, m, 64));
    float e0 = __expf(p0 - mx), e1 = __expf(p1 - mx);
    float sum = e0 + e1;
#pragma unroll
    for (int m = 1; m < 32; m <<= 1) sum += __shfl_xor(sum, m, 64);
    float inv = 1.0f / sum;
    float2 o = {e0 * inv, e1 * inv};
    *(float2*)(out + (size_t)N_NODES * 64 + (size_t)row * 64 + lane * 2) = o;  // pool1 second
  } else {          // enc half: relu
    int l = lane - 32;
    float2 o = {fmaxf(p0, 0.f), fmaxf(p1, 0.f)};
    *(float2*)(out + (size_t)row * 64 + l * 2) = o;                            // enc2 first
  }
}

extern "C" void kernel_launch(void* const* d_in, const int* in_sizes, int n_in,
                              void* d_out, int out_size, void* d_ws, size_t ws_size,
                              hipStream_t stream) {
  const float* x    = (const float*)d_in[0];
  const int*   esrc = (const int*)d_in[1];
  const int*   edst = (const int*)d_in[2];
  const float* ew   = (const float*)d_in[3];
  const float* w1   = (const float*)d_in[4];
  // d_in[5]=b1, d_in[7]=bp, d_in[9]=b2 are zero AND cancel under PairNorm centering
  const float* wp   = (const float*)d_in[6];
  const float* w2   = (const float*)d_in[8];
  float* out = (float*)d_out;

  char* ws = (char*)d_ws;
  size_t off = 0;
  auto alloc = [&](size_t bytes) {
    char* p = ws + off;
    off += (bytes + 255) & ~(size_t)255;
    return p;
  };
  uint16_t* support = (uint16_t*)alloc((size_t)N_NODES * 128 * 2);  // bf16
  uint16_t* agg     = (uint16_t*)alloc((size_t)N_NODES * 128 * 2);  // bf16; reused as enc1 in place
  int2*     rec     = (int2*)alloc((size_t)N_EDGES * 8);            // packed {src, w}
  int*      row_ptr = (int*)alloc((size_t)(N_NODES + 1) * 4);
  int*      bsum    = (int*)alloc((size_t)N_SCAN_BLOCKS * 4);
  size_t zero_start = off;
  int*      deg     = (int*)alloc((size_t)N_NODES * 4);
  int*      fill    = (int*)alloc((size_t)N_NODES * 4);
  float*    cs      = (float*)alloc(256 * 4);
  size_t zero_bytes = off - zero_start;
  uint16_t* wT1     = (uint16_t*)alloc(128 * 256 * 2);
  uint16_t* wTc     = (uint16_t*)alloc(128 * 128 * 2);
  (void)ws_size; (void)in_sizes; (void)n_in; (void)out_size;

  hipMemsetAsync(deg, 0, zero_bytes, stream);

  // CSR build (reused by both SpMMs)
  k_hist<<<(N_EDGES + 255) / 256, 256, 0, stream>>>(edst, deg);
  k_scan_local<<<N_SCAN_BLOCKS, 256, 0, stream>>>(deg, row_ptr, bsum);
  k_scan_blocks<<<1, 128, 0, stream>>>(bsum);
  k_scan_add<<<(N_NODES + 255) / 256, 256, 0, stream>>>(row_ptr, bsum);
  k_scatter<<<(N_EDGES + 255) / 256, 256, 0, stream>>>(esrc, edst, ew, row_ptr, fill, rec);
  k_pack<<<192, 256, 0, stream>>>(w1, wp, w2, wT1, wTc);

  // Layer 1
  k_gemm1<<<(N_NODES + 63) / 64, 256, 0, stream>>>(x, wT1, support, N_NODES);
  k_spmm<<<(N_NODES + 3) / 4, 256, 0, stream>>>(support, row_ptr, rec, agg);
  k_colsum<<<(N_NODES + 255) / 256, 256, 0, stream>>>(agg, cs);
  k_pn1<<<(N_NODES + 3) / 4, 256, 0, stream>>>(agg, cs);  // agg := enc1 (in place)

  // Layer 2 (pool + enc fused: support_cat = enc1 @ [wp|w2])
  k_gemm2<<<(N_NODES + 63) / 64, 256, 0, stream>>>(agg, wTc, support, N_NODES);
  k_spmm<<<(N_NODES + 3) / 4, 256, 0, stream>>>(support, row_ptr, rec, agg);
  k_colsum<<<(N_NODES + 255) / 256, 256, 0, stream>>>(agg, cs + 128);
  k_final<<<(N_NODES + 3) / 4, 256, 0, stream>>>(agg, cs + 128, out);
}

// Round 6
// 669.833 us; speedup vs baseline: 1.7543x; 1.0054x over previous
//
#include <hip/hip_runtime.h>
#include <stdint.h>

#define N_NODES 100000
#define N_EDGES 1600000
#define N_SCAN_BLOCKS ((N_NODES + 1023) / 1024)   // 98

typedef __attribute__((ext_vector_type(8))) short bf16x8;
typedef __attribute__((ext_vector_type(4))) float f32x4;

__device__ __forceinline__ uint32_t f2bf(float f) {
  uint32_t u = __float_as_uint(f);
  u += 0x7fffu + ((u >> 16) & 1);   // RNE
  return u >> 16;
}
__device__ __forceinline__ float bf_lo(uint32_t v) { return __uint_as_float(v << 16); }
__device__ __forceinline__ float bf_hi(uint32_t v) { return __uint_as_float(v & 0xffff0000u); }
__device__ __forceinline__ uint32_t pack2(float a, float b) { return f2bf(a) | (f2bf(b) << 16); }

// ---------- CSR build ----------
__global__ void k_hist(const int* __restrict__ dst, int* __restrict__ deg) {
  int e = blockIdx.x * 256 + threadIdx.x;
  if (e < N_EDGES) atomicAdd(&deg[dst[e]], 1);
}

// Hierarchical scan stage 1: per-block (1024 elems) exclusive scan + block total.
__global__ __launch_bounds__(256) void k_scan_local(const int* __restrict__ deg,
                                                    int* __restrict__ row_ptr,
                                                    int* __restrict__ blocksum) {
  __shared__ int lds[256];
  int base = blockIdx.x * 1024 + threadIdx.x * 4;
  int v0 = (base     < N_NODES) ? deg[base]     : 0;
  int v1 = (base + 1 < N_NODES) ? deg[base + 1] : 0;
  int v2 = (base + 2 < N_NODES) ? deg[base + 2] : 0;
  int v3 = (base + 3 < N_NODES) ? deg[base + 3] : 0;
  int tsum = v0 + v1 + v2 + v3;
  lds[threadIdx.x] = tsum;
  __syncthreads();
  for (int off = 1; off < 256; off <<= 1) {
    int t = (threadIdx.x >= (unsigned)off) ? lds[threadIdx.x - off] : 0;
    __syncthreads();
    lds[threadIdx.x] += t;
    __syncthreads();
  }
  int run = lds[threadIdx.x] - tsum;   // exclusive prefix of this thread's chunk
  if (base     < N_NODES) row_ptr[base]     = run;            run += v0;
  if (base + 1 < N_NODES) row_ptr[base + 1] = run;            run += v1;
  if (base + 2 < N_NODES) row_ptr[base + 2] = run;            run += v2;
  if (base + 3 < N_NODES) row_ptr[base + 3] = run;
  if (threadIdx.x == 255) blocksum[blockIdx.x] = lds[255];
}

// Stage 2: exclusive scan of the 98 block sums (single tiny block).
__global__ __launch_bounds__(128) void k_scan_blocks(int* __restrict__ blocksum) {
  __shared__ int lds[128];
  int v = (threadIdx.x < N_SCAN_BLOCKS) ? blocksum[threadIdx.x] : 0;
  lds[threadIdx.x] = v;
  __syncthreads();
  for (int off = 1; off < 128; off <<= 1) {
    int t = (threadIdx.x >= (unsigned)off) ? lds[threadIdx.x - off] : 0;
    __syncthreads();
    lds[threadIdx.x] += t;
    __syncthreads();
  }
  if (threadIdx.x < N_SCAN_BLOCKS) blocksum[threadIdx.x] = lds[threadIdx.x] - v;  // exclusive
}

// Stage 3: add block offsets; row_ptr[N] is the compile-time edge count.
__global__ __launch_bounds__(256) void k_scan_add(int* __restrict__ row_ptr,
                                                  const int* __restrict__ blocksum) {
  int i = blockIdx.x * 256 + threadIdx.x;
  if (i < N_NODES) row_ptr[i] += blocksum[i >> 10];
  if (i == 0) row_ptr[N_NODES] = N_EDGES;
}

// Direct scatter with per-node fill counters (100k counters -> ~16 atomics each;
// the 391-counter bucket variant serialized at 557us — keep counters plentiful).
__global__ void k_scatter(const int* __restrict__ src, const int* __restrict__ dst,
                          const float* __restrict__ w, const int* __restrict__ row_ptr,
                          int* __restrict__ fill, int2* __restrict__ rec) {
  int e = blockIdx.x * 256 + threadIdx.x;
  if (e < N_EDGES) {
    int d = dst[e];
    int pos = row_ptr[d] + atomicAdd(&fill[d], 1);
    rec[pos] = make_int2(src[e], __float_as_int(w[e]));
  }
}

// ---------- pack fp32 weights -> bf16, transposed [n][k] ----------
__global__ void k_pack(const float* __restrict__ w1, const float* __restrict__ wp,
                       const float* __restrict__ w2, uint16_t* __restrict__ wT1,
                       uint16_t* __restrict__ wTc) {
  int i = blockIdx.x * 256 + threadIdx.x;
  if (i < 128 * 256) {            // wT1[n*256+k] = bf16(w1[k*128+n])
    int n = i >> 8, k = i & 255;
    wT1[n * 256 + k] = (uint16_t)f2bf(w1[k * 128 + n]);
  }
  int j = i - 128 * 256;
  if (j >= 0 && j < 128 * 128) {  // wTc[n*128+k] = bf16([wp|w2] col n, row k)
    int n = j >> 7, k = j & 127;
    wTc[n * 128 + k] = (uint16_t)f2bf((n < 64) ? wp[k * 64 + n] : w2[k * 64 + (n - 64)]);
  }
}

// ---------- GEMM1: A[M,256]fp32 @ W[256,128]bf16 -> C[M,128]bf16 ----------
// A-row fragments fully prefetched into registers: 16 independent float4
// loads in flight per wave (16 KB) instead of 2 -> latency-depth fix.
__global__ __launch_bounds__(256) void k_gemm1(const float* __restrict__ A,
                                               const uint16_t* __restrict__ wT,
                                               uint16_t* __restrict__ C, int M) {
  int wave = threadIdx.x >> 6, lane = threadIdx.x & 63;
  int m0 = (blockIdx.x * 4 + wave) * 16;
  int quad = lane >> 4, mcol = lane & 15;
  int arow = m0 + mcol;
  bool av = arow < M;

  float4 abuf[16];
  const float* ap = A + (size_t)arow * 256 + quad * 8;
  if (av) {
#pragma unroll
    for (int t = 0; t < 8; t++) {
      abuf[2 * t]     = *(const float4*)(ap + t * 32);
      abuf[2 * t + 1] = *(const float4*)(ap + t * 32 + 4);
    }
  } else {
#pragma unroll
    for (int t = 0; t < 16; t++) abuf[t] = (float4){0.f, 0.f, 0.f, 0.f};
  }

  const uint16_t* bp = wT + (size_t)mcol * 256 + quad * 8;

  f32x4 acc[8];
#pragma unroll
  for (int nt = 0; nt < 8; nt++) acc[nt] = (f32x4){0.f, 0.f, 0.f, 0.f};

#pragma unroll
  for (int it = 0; it < 8; it++) {
    float4 lo = abuf[2 * it], hi = abuf[2 * it + 1];
    bf16x8 a;
    a[0] = (short)f2bf(lo.x); a[1] = (short)f2bf(lo.y);
    a[2] = (short)f2bf(lo.z); a[3] = (short)f2bf(lo.w);
    a[4] = (short)f2bf(hi.x); a[5] = (short)f2bf(hi.y);
    a[6] = (short)f2bf(hi.z); a[7] = (short)f2bf(hi.w);
#pragma unroll
    for (int nt = 0; nt < 8; nt++) {
      bf16x8 b = *(const bf16x8*)(bp + (size_t)nt * 16 * 256 + it * 32);
      acc[nt] = __builtin_amdgcn_mfma_f32_16x16x32_bf16(a, b, acc[nt], 0, 0, 0);
    }
  }
#pragma unroll
  for (int r = 0; r < 4; r++) {
    int row = m0 + quad * 4 + r;
    if (row < M) {
#pragma unroll
      for (int nt = 0; nt < 8; nt++)
        C[(size_t)row * 128 + nt * 16 + mcol] = (uint16_t)f2bf(acc[nt][r]);
    }
  }
}

// ---------- GEMM2: A[M,128]bf16 @ W[128,128]bf16 -> C[M,128]bf16 ----------
// Same prefetch treatment: all 4 A-fragments loaded up-front.
__global__ __launch_bounds__(256) void k_gemm2(const uint16_t* __restrict__ A,
                                               const uint16_t* __restrict__ wT,
                                               uint16_t* __restrict__ C, int M) {
  int wave = threadIdx.x >> 6, lane = threadIdx.x & 63;
  int m0 = (blockIdx.x * 4 + wave) * 16;
  int quad = lane >> 4, mcol = lane & 15;
  int arow = m0 + mcol;
  bool av = arow < M;

  bf16x8 abuf[4];
  const uint16_t* ap = A + (size_t)arow * 128 + quad * 8;
  if (av) {
#pragma unroll
    for (int t = 0; t < 4; t++) abuf[t] = *(const bf16x8*)(ap + t * 32);
  } else {
#pragma unroll
    for (int t = 0; t < 4; t++) abuf[t] = (bf16x8){};
  }

  const uint16_t* bp = wT + (size_t)mcol * 128 + quad * 8;

  f32x4 acc[8];
#pragma unroll
  for (int nt = 0; nt < 8; nt++) acc[nt] = (f32x4){0.f, 0.f, 0.f, 0.f};

#pragma unroll
  for (int it = 0; it < 4; it++) {
#pragma unroll
    for (int nt = 0; nt < 8; nt++) {
      bf16x8 b = *(const bf16x8*)(bp + (size_t)nt * 16 * 128 + it * 32);
      acc[nt] = __builtin_amdgcn_mfma_f32_16x16x32_bf16(abuf[it], b, acc[nt], 0, 0, 0);
    }
  }
#pragma unroll
  for (int r = 0; r < 4; r++) {
    int row = m0 + quad * 4 + r;
    if (row < M) {
#pragma unroll
      for (int nt = 0; nt < 8; nt++)
        C[(size_t)row * 128 + nt * 16 + mcol] = (uint16_t)f2bf(acc[nt][r]);
    }
  }
}

// ---------- SpMM: agg[r,:] = sum_e w_e * support[src_e,:]  (CSR, 1 wave/row, unroll 8) ----------
__global__ __launch_bounds__(256) void k_spmm(const uint16_t* __restrict__ sup,
                                              const int* __restrict__ row_ptr,
                                              const int2* __restrict__ rec,
                                              uint16_t* __restrict__ agg) {
  int row = blockIdx.x * 4 + (threadIdx.x >> 6);
  if (row >= N_NODES) return;
  int lane = threadIdx.x & 63;
  int s = row_ptr[row], e = row_ptr[row + 1];
  float a0 = 0.f, a1 = 0.f;
  int i = s;
  for (; i + 8 <= e; i += 8) {
    int2 r[8];
    uint32_t v[8];
#pragma unroll
    for (int u = 0; u < 8; u++) r[u] = rec[i + u];
#pragma unroll
    for (int u = 0; u < 8; u++)
      v[u] = *(const uint32_t*)(sup + (size_t)r[u].x * 128 + lane * 2);
#pragma unroll
    for (int u = 0; u < 8; u++) {
      float w = __int_as_float(r[u].y);
      a0 += w * bf_lo(v[u]);
      a1 += w * bf_hi(v[u]);
    }
  }
  for (; i < e; i++) {
    int2 r = rec[i];
    uint32_t v = *(const uint32_t*)(sup + (size_t)r.x * 128 + lane * 2);
    float w = __int_as_float(r.y);
    a0 += w * bf_lo(v);
    a1 += w * bf_hi(v);
  }
  *(uint32_t*)(agg + (size_t)row * 128 + lane * 2) = pack2(a0, a1);
}

// ---------- column sums (for PairNorm centering) ----------
__global__ __launch_bounds__(256) void k_colsum(const uint16_t* __restrict__ agg,
                                                float* __restrict__ cs) {
  __shared__ float sd[256];
  int col = threadIdx.x & 127, half = threadIdx.x >> 7;
  int r0 = blockIdx.x * 256;
  float local = 0.f;
  for (int r = r0 + half; r < r0 + 256 && r < N_NODES; r += 2)
    local += __uint_as_float(((uint32_t)agg[(size_t)r * 128 + col]) << 16);
  sd[threadIdx.x] = local;
  __syncthreads();
  if (threadIdx.x < 128) atomicAdd(&cs[col], sd[threadIdx.x] + sd[threadIdx.x + 128]);
}

// ---------- PairNorm-SI + ReLU, IN PLACE on agg (bf16) ----------
__global__ __launch_bounds__(256) void k_pn1(uint16_t* __restrict__ agg,
                                             const float* __restrict__ cs) {
  int row = blockIdx.x * 4 + (threadIdx.x >> 6);
  if (row >= N_NODES) return;
  int lane = threadIdx.x & 63;
  const float invn = 1.0f / (float)N_NODES;
  uint32_t v = *(const uint32_t*)(agg + (size_t)row * 128 + lane * 2);
  float h0 = bf_lo(v) - cs[lane * 2] * invn;
  float h1 = bf_hi(v) - cs[lane * 2 + 1] * invn;
  float ss = h0 * h0 + h1 * h1;
#pragma unroll
  for (int m = 1; m < 64; m <<= 1) ss += __shfl_xor(ss, m, 64);
  float rinv = rsqrtf(1e-6f + ss);
  *(uint32_t*)(agg + (size_t)row * 128 + lane * 2) =
      pack2(fmaxf(h0 * rinv, 0.f), fmaxf(h1 * rinv, 0.f));
}

// ---------- final: agg cols 0..63 -> pool1 (pairnorm+softmax), 64..127 -> enc2 (pairnorm+relu), fp32 out ----------
__global__ __launch_bounds__(256) void k_final(const uint16_t* __restrict__ agg,
                                               const float* __restrict__ cs,
                                               float* __restrict__ out) {
  int row = blockIdx.x * 4 + (threadIdx.x >> 6);
  if (row >= N_NODES) return;
  int lane = threadIdx.x & 63;
  const float invn = 1.0f / (float)N_NODES;
  uint32_t v = *(const uint32_t*)(agg + (size_t)row * 128 + lane * 2);
  float h0 = bf_lo(v) - cs[lane * 2] * invn;
  float h1 = bf_hi(v) - cs[lane * 2 + 1] * invn;
  float ss = h0 * h0 + h1 * h1;
#pragma unroll
  for (int m = 1; m < 32; m <<= 1) ss += __shfl_xor(ss, m, 64);  // half-wave reduce (each 64-col half separately)
  float rinv = rsqrtf(1e-6f + ss);
  float p0 = h0 * rinv, p1 = h1 * rinv;
  if (lane < 32) {  // pool half: softmax over 64 cols spread across lanes 0..31
    float mx = fmaxf(p0, p1);
#pragma unroll
    for (int m = 1; m < 32; m <<= 1) mx = fmaxf(mx, __shfl_xor(mx, m, 64));
    float e0 = __expf(p0 - mx), e1 = __expf(p1 - mx);
    float sum = e0 + e1;
#pragma unroll
    for (int m = 1; m < 32; m <<= 1) sum += __shfl_xor(sum, m, 64);
    float inv = 1.0f / sum;
    float2 o = {e0 * inv, e1 * inv};
    *(float2*)(out + (size_t)N_NODES * 64 + (size_t)row * 64 + lane * 2) = o;  // pool1 second
  } else {          // enc half: relu
    int l = lane - 32;
    float2 o = {fmaxf(p0, 0.f), fmaxf(p1, 0.f)};
    *(float2*)(out + (size_t)row * 64 + l * 2) = o;                            // enc2 first
  }
}

extern "C" void kernel_launch(void* const* d_in, const int* in_sizes, int n_in,
                              void* d_out, int out_size, void* d_ws, size_t ws_size,
                              hipStream_t stream) {
  const float* x    = (const float*)d_in[0];
  const int*   esrc = (const int*)d_in[1];
  const int*   edst = (const int*)d_in[2];
  const float* ew   = (const float*)d_in[3];
  const float* w1   = (const float*)d_in[4];
  // d_in[5]=b1, d_in[7]=bp, d_in[9]=b2 are zero AND cancel under PairNorm centering
  const float* wp   = (const float*)d_in[6];
  const float* w2   = (const float*)d_in[8];
  float* out = (float*)d_out;

  char* ws = (char*)d_ws;
  size_t off = 0;
  auto alloc = [&](size_t bytes) {
    char* p = ws + off;
    off += (bytes + 255) & ~(size_t)255;
    return p;
  };
  uint16_t* support = (uint16_t*)alloc((size_t)N_NODES * 128 * 2);  // bf16
  uint16_t* agg     = (uint16_t*)alloc((size_t)N_NODES * 128 * 2);  // bf16; reused as enc1 in place
  int2*     rec     = (int2*)alloc((size_t)N_EDGES * 8);            // packed {src, w}
  int*      row_ptr = (int*)alloc((size_t)(N_NODES + 1) * 4);
  int*      bsum    = (int*)alloc((size_t)N_SCAN_BLOCKS * 4);
  size_t zero_start = off;
  int*      deg     = (int*)alloc((size_t)N_NODES * 4);
  int*      fill    = (int*)alloc((size_t)N_NODES * 4);
  float*    cs      = (float*)alloc(256 * 4);
  size_t zero_bytes = off - zero_start;
  uint16_t* wT1     = (uint16_t*)alloc(128 * 256 * 2);
  uint16_t* wTc     = (uint16_t*)alloc(128 * 128 * 2);
  (void)ws_size; (void)in_sizes; (void)n_in; (void)out_size;

  hipMemsetAsync(deg, 0, zero_bytes, stream);

  // CSR build (reused by both SpMMs)
  k_hist<<<(N_EDGES + 255) / 256, 256, 0, stream>>>(edst, deg);
  k_scan_local<<<N_SCAN_BLOCKS, 256, 0, stream>>>(deg, row_ptr, bsum);
  k_scan_blocks<<<1, 128, 0, stream>>>(bsum);
  k_scan_add<<<(N_NODES + 255) / 256, 256, 0, stream>>>(row_ptr, bsum);
  k_scatter<<<(N_EDGES + 255) / 256, 256, 0, stream>>>(esrc, edst, ew, row_ptr, fill, rec);
  k_pack<<<192, 256, 0, stream>>>(w1, wp, w2, wT1, wTc);

  // Layer 1
  k_gemm1<<<(N_NODES + 63) / 64, 256, 0, stream>>>(x, wT1, support, N_NODES);
  k_spmm<<<(N_NODES + 3) / 4, 256, 0, stream>>>(support, row_ptr, rec, agg);
  k_colsum<<<(N_NODES + 255) / 256, 256, 0, stream>>>(agg, cs);
  k_pn1<<<(N_NODES + 3) / 4, 256, 0, stream>>>(agg, cs);  // agg := enc1 (in place)

  // Layer 2 (pool + enc fused: support_cat = enc1 @ [wp|w2])
  k_gemm2<<<(N_NODES + 63) / 64, 256, 0, stream>>>(agg, wTc, support, N_NODES);
  k_spmm<<<(N_NODES + 3) / 4, 256, 0, stream>>>(support, row_ptr, rec, agg);
  k_colsum<<<(N_NODES + 255) / 256, 256, 0, stream>>>(agg, cs + 128);
  k_final<<<(N_NODES + 3) / 4, 256, 0, stream>>>(agg, cs + 128, out);
}